// Round 7
// baseline (5282.419 us; speedup 1.0000x reference)
//
#include <hip/hip_runtime.h>

#define B_ 128
#define T_ 2048

typedef float vf32 __attribute__((ext_vector_type(32)));

__device__ __forceinline__ float fast_sigmoid(float x){
    return 1.0f / (1.0f + __expf(-x));
}
__device__ __forceinline__ float fast_tanh(float x){
    float a = fabsf(x);
    float e = __expf(2.0f*a);
    float r = 1.0f - 2.0f/(e + 1.0f);   // e=inf -> r=1, no NaN
    return (x < 0.0f) ? -r : r;
}

// ---------------------------------------------------------------------------
// R0-R6 established: per-step time (1.66us) is invariant to sync mechanism
// (4 barriers == flags), spill vs no-spill, VGPR 88-124.  The bottleneck is
// the CONTENT of the serial chains (LDS round-trips, cross-wave handoffs,
// shuffle stages), not sync overhead or register traffic.  So: split the scan
// into two kernels with minimal per-step chains.
//
// KERNEL A (lstm): quad-gate layout.  Lane 4u+g of wave w owns gate row
// 64g + (16w+u): i/f/g/o of hidden unit u'=16w+u live in ONE 4-lane quad.
// After the 96-FMA dot, 2 shfl_xor stages all-gather the quad's 4 gates --
// the gates NEVER go through LDS and there is no cross-wave activation
// handoff.  Every lane redundantly computes c/h (replication is free).
// ONE barrier per step.  h(t) streams to workspace for kernel B.
// ---------------------------------------------------------------------------
__global__ __launch_bounds__(256)
__attribute__((amdgpu_waves_per_eu(1, 2)))
void lstm_kernel(
    const float* __restrict__ obs,
    const float* __restrict__ Wih,
    const float* __restrict__ Whh,
    const float* __restrict__ bih,
    const float* __restrict__ bhh,
    float* __restrict__ hout)          // [B][T][64] workspace
{
    __shared__ __align__(16) float h_s[2][64];
    __shared__ __align__(16) float oring[8][32];

    const int tid  = threadIdx.x;
    const int w    = tid >> 6;
    const int lane = tid & 63;
    const int g    = lane & 3;          // gate 0..3 (i,f,g,o)
    const int u    = lane >> 2;         // 0..15
    const int uu   = w*16 + u;          // hidden unit 0..63
    const int row  = g*64 + uu;         // row of [Wih|Whh]
    const int b    = blockIdx.x;

    vf32 V0, V1, V2;
    #pragma unroll
    for (int k = 0; k < 32; k++) { V0[k]=0.f; V1[k]=0.f; V2[k]=0.f; }
    #pragma unroll
    for (int k = 0; k < 32; k++) V0[k] = Wih[row*32 + k];
    #pragma unroll
    for (int k = 0; k < 32; k++) V1[k] = Whh[row*64 + k];
    #pragma unroll
    for (int k = 0; k < 32; k++) V2[k] = Whh[row*64 + 32 + k];
    const float biasg = bih[row] + bhh[row];

    float carry = 0.f;
    if (tid < 128) oring[tid >> 5][tid & 31] = obs[(size_t)b*T_*32 + tid]; // t=0..3
    if (g == 1 && uu < 32) carry = obs[((size_t)b*T_ + 4)*32 + uu];        // t=4
    if (tid < 64) h_s[0][tid] = 0.f;    // h(-1)
    __syncthreads();

    float c_st = 0.f;
    for (int t = 0; t < T_; ++t) {
        const float4* ob = (const float4*)oring[t & 7];
        const float4* hp = (const float4*)h_s[t & 1];
        float a0 = biasg, a1 = 0.f, a2 = 0.f, a3 = 0.f;
        #pragma unroll
        for (int k4 = 0; k4 < 8; k4++) {
            float4 o = ob[k4];
            a0 += V0[k4*4+0]*o.x;
            a1 += V0[k4*4+1]*o.y;
            a2 += V0[k4*4+2]*o.z;
            a3 += V0[k4*4+3]*o.w;
        }
        #pragma unroll
        for (int k4 = 0; k4 < 8; k4++) {
            float4 h = hp[k4];
            a0 += V1[k4*4+0]*h.x;
            a1 += V1[k4*4+1]*h.y;
            a2 += V1[k4*4+2]*h.z;
            a3 += V1[k4*4+3]*h.w;
        }
        #pragma unroll
        for (int k4 = 0; k4 < 8; k4++) {
            float4 h = hp[8 + k4];
            a0 += V2[k4*4+0]*h.x;
            a1 += V2[k4*4+1]*h.y;
            a2 += V2[k4*4+2]*h.z;
            a3 += V2[k4*4+3]*h.w;
        }
        const float G = (a0 + a1) + (a2 + a3);

        // quad all-gather: x1 = gate(g^1), x2 = gate(g^2), x3 = gate(g^3)
        const float x1 = __shfl_xor(G, 1, 64);
        const float x2 = __shfl_xor(G, 2, 64);
        const float x3 = __shfl_xor(x1, 2, 64);
        const bool c1 = (g & 1), c2 = (g & 2);
        float iv = c2 ? (c1 ? x3 : x2) : (c1 ? x1 : G );   // gate 0
        float fv = c2 ? (c1 ? x2 : x3) : (c1 ? G  : x1);   // gate 1
        float gv = c2 ? (c1 ? x1 : G ) : (c1 ? x3 : x2);   // gate 2
        float ov = c2 ? (c1 ? G  : x1) : (c1 ? x2 : x3);   // gate 3

        iv = fast_sigmoid(iv);
        fv = fast_sigmoid(fv);
        gv = fast_tanh(gv);
        ov = fast_sigmoid(ov);
        c_st = fv*c_st + iv*gv;
        const float hv = ov * fast_tanh(c_st);

        if (g == 0) h_s[(t + 1) & 1][uu] = hv;                       // h(t) -> LDS
        if (g == 2) hout[((size_t)b*T_ + t)*64 + uu] = hv;           // h(t) -> global
        if (g == 1 && uu < 32) {
            if (t + 4 < T_) oring[(t + 4) & 7][uu] = carry;
            if (t + 5 < T_) carry = obs[((size_t)b*T_ + t + 5)*32 + uu];
        }
        __syncthreads();
    }
}

// ---------------------------------------------------------------------------
// KERNEL B (trans): z-chain with the h-dependent part of mv1 hoisted OFF the
// critical path.  mv1 = A1[t] (tb1 + tw1[:,:64] . h(t), z-INDEPENDENT) +
// B.z (5 FMA).  Waves 2-3 compute A1[t+4] into an LDS ring using h staged
// global->reg->LDS one iteration ahead; waves 0-1 run the serial z-chain:
//   seg1: a = A1ring + B.z ; LN butterfly ; partials -> lnp
//   seg2: LN finalize + tanh -> h1_s     (A1 waves: 64-FMA dot)
//   seg3: mv2 K-split (own 64 rows)      (A1 waves: ring write)
//   seg4: wave0: h2, mv3 (shfl gather), z + outputs
// Weight budget/lane: wave0 = 64(mv2)+5(B)+16(w3) = 85; others <= 69.
// ---------------------------------------------------------------------------
__global__ __launch_bounds__(256)
__attribute__((amdgpu_waves_per_eu(1, 2)))
void trans_kernel(
    const float* __restrict__ hsrc,     // [B][T][64] from lstm_kernel
    const float* __restrict__ tw1,
    const float* __restrict__ tb1,
    const float* __restrict__ tg,
    const float* __restrict__ tbeta,
    const float* __restrict__ tw2,
    const float* __restrict__ tb2,
    const float* __restrict__ tw3,
    const float* __restrict__ tb3,
    const float* __restrict__ z0m,
    const float* __restrict__ z0lv,
    float* __restrict__ out_tm,
    float* __restrict__ out_tlv)
{
    __shared__ __align__(16) float A1ring[8][128];
    __shared__ __align__(16) float h_stage[8][64];
    __shared__ __align__(16) float h1_s[128];
    __shared__ float p2s[64];
    __shared__ float lnp[4];
    __shared__ float z_s[8];

    const int tid  = threadIdx.x;
    const int w    = tid >> 6;
    const int lane = tid & 63;
    const int b    = blockIdx.x;

    vf32 V0, V1, V2;
    #pragma unroll
    for (int k = 0; k < 32; k++) { V0[k]=0.f; V1[k]=0.f; V2[k]=0.f; }
    float b1r = 0.f, gr = 0.f, betar = 0.f, b2r = 0.f, b3r = 0.f;

    if (w < 2) {
        const int r = w*64 + lane;               // mv1/h1 row 0..127
        #pragma unroll
        for (int k = 0; k < 5; k++) V2[k] = tw1[r*69 + 64 + k];   // B-part
        gr = tg[r]; betar = tbeta[r];
        #pragma unroll
        for (int k = 0; k < 32; k++) V0[k] = tw2[lane*128 + w*64 + k];
        #pragma unroll
        for (int k = 0; k < 32; k++) V1[k] = tw2[lane*128 + w*64 + 32 + k];
        if (w == 0) {
            b2r = tb2[lane];
            if (lane < 40) {
                #pragma unroll
                for (int k = 0; k < 16; k++)
                    V2[5 + k] = tw3[(lane>>2)*64 + (lane&3)*16 + k];
                b3r = tb3[lane >> 2];
            }
        }
    } else {
        const int rA = (w - 2)*64 + lane;        // A1 row 0..127
        #pragma unroll
        for (int k = 0; k < 32; k++) V0[k] = tw1[rA*69 + k];
        #pragma unroll
        for (int k = 0; k < 32; k++) V1[k] = tw1[rA*69 + 32 + k];
        b1r = tb1[rA];
    }

    if (tid < 5) {
        z_s[tid] = z0m[tid];
        out_tm [(size_t)b*T_*5 + tid] = z0m[tid];
        out_tlv[(size_t)b*T_*5 + tid] = z0lv[tid];
    }
    __syncthreads();

    // ---- prologue: A1[1..4] directly from global h ----
    if (w >= 2) {
        const int rA = (w - 2)*64 + lane;
        for (int tt = 1; tt <= 4 && tt < T_; ++tt) {
            const float4* hv4 = (const float4*)(hsrc + ((size_t)b*T_ + tt)*64);
            float s0 = b1r, s1 = 0.f, s2 = 0.f, s3 = 0.f;
            #pragma unroll
            for (int k4 = 0; k4 < 8; k4++) {
                float4 h = hv4[k4];
                s0 += V0[k4*4+0]*h.x;
                s1 += V0[k4*4+1]*h.y;
                s2 += V0[k4*4+2]*h.z;
                s3 += V0[k4*4+3]*h.w;
            }
            #pragma unroll
            for (int k4 = 0; k4 < 8; k4++) {
                float4 h = hv4[8 + k4];
                s0 += V1[k4*4+0]*h.x;
                s1 += V1[k4*4+1]*h.y;
                s2 += V1[k4*4+2]*h.z;
                s3 += V1[k4*4+3]*h.w;
            }
            A1ring[tt & 7][rA] = (s0 + s1) + (s2 + s3);
        }
    }
    float gl_carry = 0.f;
    if (w == 2 && 5 < T_) gl_carry = hsrc[((size_t)b*T_ + 5)*64 + lane];  // h(5)
    __syncthreads();

    float av = 0.f, a1acc = 0.f;
    for (int t = 1; t < T_; ++t) {
        // ---- seg1 ----
        if (w < 2) {
            const int r = w*64 + lane;
            av = A1ring[t & 7][r]
               + V2[0]*z_s[0] + V2[1]*z_s[1] + V2[2]*z_s[2]
               + V2[3]*z_s[3] + V2[4]*z_s[4];
            float s1 = av, s2 = av*av;
            #pragma unroll
            for (int m = 1; m < 64; m <<= 1) {
                s1 += __shfl_xor(s1, m, 64);
                s2 += __shfl_xor(s2, m, 64);
            }
            if (lane == 0) { lnp[w*2] = s1; lnp[w*2 + 1] = s2; }
        } else if (w == 2) {
            if (t + 4 < T_) h_stage[(t + 4) & 7][lane] = gl_carry;   // h(t+4)
            if (t + 5 < T_) gl_carry = hsrc[((size_t)b*T_ + t + 5)*64 + lane];
        }
        __syncthreads();

        // ---- seg2 ----
        if (w < 2) {
            const int r = w*64 + lane;
            const float mean = (lnp[0] + lnp[2]) * (1.0f/128.0f);
            const float ms   = (lnp[1] + lnp[3]) * (1.0f/128.0f);
            const float var  = fmaxf(ms - mean*mean, 0.0f);
            const float rs   = rsqrtf(var + 1e-5f);
            h1_s[r] = fast_tanh((av - mean)*rs*gr + betar);
        } else if (t + 4 < T_) {
            const float4* hv4 = (const float4*)h_stage[(t + 4) & 7];
            float s0 = b1r, s1 = 0.f, s2 = 0.f, s3 = 0.f;
            #pragma unroll
            for (int k4 = 0; k4 < 8; k4++) {
                float4 h = hv4[k4];
                s0 += V0[k4*4+0]*h.x;
                s1 += V0[k4*4+1]*h.y;
                s2 += V0[k4*4+2]*h.z;
                s3 += V0[k4*4+3]*h.w;
            }
            #pragma unroll
            for (int k4 = 0; k4 < 8; k4++) {
                float4 h = hv4[8 + k4];
                s0 += V1[k4*4+0]*h.x;
                s1 += V1[k4*4+1]*h.y;
                s2 += V1[k4*4+2]*h.z;
                s3 += V1[k4*4+3]*h.w;
            }
            a1acc = (s0 + s1) + (s2 + s3);
        }
        __syncthreads();

        // ---- seg3 ----
        if (w < 2) {
            const float4* h14 = (const float4*)(h1_s + w*64);
            float p0 = 0.f, p1 = 0.f, p2 = 0.f, p3 = 0.f;
            #pragma unroll
            for (int k4 = 0; k4 < 8; k4++) {
                float4 h = h14[k4];
                p0 += V0[k4*4+0]*h.x;
                p1 += V0[k4*4+1]*h.y;
                p2 += V0[k4*4+2]*h.z;
                p3 += V0[k4*4+3]*h.w;
            }
            #pragma unroll
            for (int k4 = 0; k4 < 8; k4++) {
                float4 h = h14[8 + k4];
                p0 += V1[k4*4+0]*h.x;
                p1 += V1[k4*4+1]*h.y;
                p2 += V1[k4*4+2]*h.z;
                p3 += V1[k4*4+3]*h.w;
            }
            av = (p0 + p1) + (p2 + p3);       // reuse av as mv2 partial
            if (w == 1) p2s[lane] = av;
        } else {
            if (t + 4 < T_) A1ring[(t + 4) & 7][(w - 2)*64 + lane] = a1acc;
        }
        __syncthreads();

        // ---- seg4 (wave 0 only) ----
        if (w == 0) {
            const float h2v = fast_tanh(b2r + av + p2s[lane]);
            const int pp = lane & 3;
            float acc = 0.f;
            #pragma unroll
            for (int k = 0; k < 16; k++)
                acc += V2[5 + k] * __shfl(h2v, pp*16 + k, 64);
            acc += __shfl_xor(acc, 1, 64);
            acc += __shfl_xor(acc, 2, 64);
            if (pp == 0 && lane < 40) {
                const int j = lane >> 2;      // 0..9
                const float val = b3r + acc;
                const size_t row = (size_t)b*T_ + t;
                if (j < 5) {
                    z_s[j] = val;
                    out_tm[row*5 + j] = val;
                } else {
                    out_tlv[row*5 + (j - 5)] = fminf(10.0f, fmaxf(-10.0f, val));
                }
            }
        }
        __syncthreads();
    }
}

// ---------------------------------------------------------------------------
// Observation decoder (unchanged): one wave per row; weights in static LDS;
// h1/h2 staged per-wave in LDS, broadcast float4 re-reads; 4-way split accs.
// ---------------------------------------------------------------------------
#define DEC_BLOCKS 512

__global__ __launch_bounds__(512) void dec_kernel(
    const float* __restrict__ ow1,
    const float* __restrict__ ob1,
    const float* __restrict__ og,
    const float* __restrict__ obeta,
    const float* __restrict__ ow2,
    const float* __restrict__ ob2,
    const float* __restrict__ ow3,
    const float* __restrict__ ob3,
    const float* __restrict__ tmeans,
    float* __restrict__ out_om,
    float* __restrict__ out_olv)
{
    __shared__ float w1s[640];
    __shared__ float b1s[128], gs[128], bes[128];
    __shared__ float w2s[8192];
    __shared__ float b2s[64];
    __shared__ float w3s[4096];
    __shared__ float b3s[64];
    __shared__ __align__(16) float h1s[8][128];
    __shared__ __align__(16) float h2s[8][64];

    const int tid = threadIdx.x;
    for (int idx = tid; idx < 640; idx += 512) w1s[idx] = ow1[idx];
    for (int idx = tid; idx < 128; idx += 512) {
        b1s[idx] = ob1[idx]; gs[idx] = og[idx]; bes[idx] = obeta[idx];
    }
    for (int idx = tid; idx < 8192; idx += 512) {
        int k = idx >> 6, j = idx & 63;
        w2s[idx] = ow2[j*128 + k];
    }
    for (int idx = tid; idx < 4096; idx += 512) {
        int k = idx >> 6, j = idx & 63;
        w3s[idx] = ow3[j*64 + k];
    }
    for (int idx = tid; idx < 64; idx += 512) { b2s[idx] = ob2[idx]; b3s[idx] = ob3[idx]; }
    __syncthreads();

    const int lane   = tid & 63;
    const int wv     = tid >> 6;
    const int gwave  = (blockIdx.x * 512 + tid) >> 6;
    const int nwaves = DEC_BLOCKS * 8;
    const int j0 = lane, j1 = lane + 64;

    for (int row = gwave; row < B_*T_; row += nwaves) {
        const float z0v = tmeans[(size_t)row*5 + 0];
        const float z1v = tmeans[(size_t)row*5 + 1];
        const float z2v = tmeans[(size_t)row*5 + 2];
        const float z3v = tmeans[(size_t)row*5 + 3];
        const float z4v = tmeans[(size_t)row*5 + 4];

        float a = b1s[j0] + w1s[j0*5+0]*z0v + w1s[j0*5+1]*z1v + w1s[j0*5+2]*z2v
                + w1s[j0*5+3]*z3v + w1s[j0*5+4]*z4v;
        float bb = b1s[j1] + w1s[j1*5+0]*z0v + w1s[j1*5+1]*z1v + w1s[j1*5+2]*z2v
                 + w1s[j1*5+3]*z3v + w1s[j1*5+4]*z4v;
        float s1 = a + bb, s2 = a*a + bb*bb;
        #pragma unroll
        for (int m = 1; m < 64; m <<= 1) {
            s1 += __shfl_xor(s1, m, 64);
            s2 += __shfl_xor(s2, m, 64);
        }
        const float mean = s1 * (1.0f/128.0f);
        const float var  = fmaxf(s2 * (1.0f/128.0f) - mean*mean, 0.0f);
        const float rs   = rsqrtf(var + 1e-5f);
        const float h1a  = fast_tanh((a  - mean)*rs*gs[j0] + bes[j0]);
        const float h1b  = fast_tanh((bb - mean)*rs*gs[j1] + bes[j1]);

        h1s[wv][lane]      = h1a;
        h1s[wv][64 + lane] = h1b;
        __builtin_amdgcn_wave_barrier();

        float acc2a = b2s[lane], acc2b = 0.f, acc2c = 0.f, acc2d = 0.f;
        const float4* h14 = (const float4*)(h1s[wv]);
        #pragma unroll
        for (int k4 = 0; k4 < 32; k4++) {
            float4 h = h14[k4];
            acc2a += h.x * w2s[(k4*4+0)*64 + lane];
            acc2b += h.y * w2s[(k4*4+1)*64 + lane];
            acc2c += h.z * w2s[(k4*4+2)*64 + lane];
            acc2d += h.w * w2s[(k4*4+3)*64 + lane];
        }
        const float h2v = fast_tanh(acc2a + acc2b + acc2c + acc2d);

        h2s[wv][lane] = h2v;
        __builtin_amdgcn_wave_barrier();

        float acc3a = b3s[lane], acc3b = 0.f, acc3c = 0.f, acc3d = 0.f;
        const float4* h24 = (const float4*)(h2s[wv]);
        #pragma unroll
        for (int k4 = 0; k4 < 16; k4++) {
            float4 h = h24[k4];
            acc3a += h.x * w3s[(k4*4+0)*64 + lane];
            acc3b += h.y * w3s[(k4*4+1)*64 + lane];
            acc3c += h.z * w3s[(k4*4+2)*64 + lane];
            acc3d += h.w * w3s[(k4*4+3)*64 + lane];
        }
        const float acc3 = acc3a + acc3b + acc3c + acc3d;

        if (lane < 32) {
            out_om[(size_t)row*32 + lane] = acc3;
        } else {
            out_olv[(size_t)row*32 + (lane - 32)] = fminf(10.0f, fmaxf(-10.0f, acc3));
        }
    }
}

extern "C" void kernel_launch(void* const* d_in, const int* in_sizes, int n_in,
                              void* d_out, int out_size, void* d_ws, size_t ws_size,
                              hipStream_t stream) {
    const float* obs  = (const float*)d_in[0];
    const float* Wih  = (const float*)d_in[1];
    const float* Whh  = (const float*)d_in[2];
    const float* bih  = (const float*)d_in[3];
    const float* bhh  = (const float*)d_in[4];
    const float* tw1  = (const float*)d_in[5];
    const float* tb1  = (const float*)d_in[6];
    const float* tg   = (const float*)d_in[7];
    const float* tbe  = (const float*)d_in[8];
    const float* tw2  = (const float*)d_in[9];
    const float* tb2  = (const float*)d_in[10];
    const float* tw3  = (const float*)d_in[11];
    const float* tb3  = (const float*)d_in[12];
    const float* ow1  = (const float*)d_in[13];
    const float* ob1  = (const float*)d_in[14];
    const float* og   = (const float*)d_in[15];
    const float* obe  = (const float*)d_in[16];
    const float* ow2  = (const float*)d_in[17];
    const float* ob2  = (const float*)d_in[18];
    const float* ow3  = (const float*)d_in[19];
    const float* ob3  = (const float*)d_in[20];
    const float* z0m  = (const float*)d_in[21];
    const float* z0lv = (const float*)d_in[22];

    float* out0 = (float*)d_out;                   // obs_means   (B,T,32)
    float* out1 = out0 + (size_t)B_*T_*32;         // obs_logvars (B,T,32)
    float* out2 = out1 + (size_t)B_*T_*32;         // trans_means (B,T,5)
    float* out3 = out2 + (size_t)B_*T_*5;          // trans_logvars

    float* hbuf = (float*)d_ws;                    // [B][T][64] = 64 MiB

    lstm_kernel<<<B_, 256, 0, stream>>>(obs, Wih, Whh, bih, bhh, hbuf);

    trans_kernel<<<B_, 256, 0, stream>>>(hbuf, tw1, tb1, tg, tbe,
                                         tw2, tb2, tw3, tb3,
                                         z0m, z0lv, out2, out3);

    dec_kernel<<<DEC_BLOCKS, 512, 0, stream>>>(
        ow1, ob1, og, obe, ow2, ob2, ow3, ob3, out2, out0, out1);
}

// Round 8
// 3135.621 us; speedup vs baseline: 1.6846x; 1.6846x over previous
//
#include <hip/hip_runtime.h>

#define B_ 128
#define T_ 2048

typedef float vf32 __attribute__((ext_vector_type(32)));

__device__ __forceinline__ float fast_sigmoid(float x){
    return 1.0f / (1.0f + __expf(-x));
}
__device__ __forceinline__ float fast_tanh(float x){
    float a = fabsf(x);
    float e = __expf(2.0f*a);
    float r = 1.0f - 2.0f/(e + 1.0f);   // e=inf -> r=1, no NaN
    return (x < 0.0f) ? -r : r;
}

// LDS flag sync helpers (workgroup scope, acquire/release) -- R6-validated
__device__ __forceinline__ void wait_ge(int* p, int v){
    while (__hip_atomic_load(p, __ATOMIC_ACQUIRE, __HIP_MEMORY_SCOPE_WORKGROUP) < v) { }
}
__device__ __forceinline__ void st_rel(int* p, int v){
    __hip_atomic_store(p, v, __ATOMIC_RELEASE, __HIP_MEMORY_SCOPE_WORKGROUP);
}

// ---------------------------------------------------------------------------
// Merged scan: one workgroup per batch b, 8 waves, NO in-loop __syncthreads.
// R7 measured the chains separately: lstm(1 barrier)=0.95us/step,
// trans(4 barriers)=1.42us/step; serial kernels lost the overlap (4.85ms).
// This kernel overlaps them again AND cuts the trans chain to 2 syncs.
//
//   waves 0-3: quad-gate LSTM (R7 structure).  Lane 4u+g of wave w owns gate
//     row g*64+(w*16+u); gates all-gather via 3 shfl_xor (no LDS).  h(t) ->
//     hring (8 deep).  Publishes hflag[w]=t.  Guards: hflag[*]>=t-1,
//     aflag[*]>=t-8 (A1 waves done reading hring slot t&7).
//   waves 6-7: A1 producers.  A1[t] = tb1 + tw1[:, :64] . h(t)  (row =
//     (wid-6)*64+lane, 64 w/lane, h from hring as float4 broadcasts) ->
//     A1ring (8 deep).  Guards: hflag[*]>=t, ttag>=t-8.  Publishes aflag.
//   waves 4-5: z-chain, 2 syncs/step.  Each wave REDUNDANTLY computes mv1
//     for all 128 rows (2 rows/lane: 2 A1ring reads + 10 z-FMAs) -> in-wave
//     LN butterfly (12 shfl_xor; no cross-wave stats) -> own h1 half ->
//     wave-local LDS strip (wave_barrier only) -> mv2 K-split (64 w/lane) ->
//     wave5 p2s+p2flag -> wave4: h2, mv3 (shfl gather), z + outputs, ttag.
//
// Deadlock-freedom (induction): LSTM blocked needs tL>=tA+8; A1 blocked needs
// tL<=tA or tT<tA-7; trans blocked needs tA<=tT.  Combining any blocking set
// yields a contradiction, so some group can always advance.
// Register roles (union storage V0..V2, 96 slots max -- R3 invariant):
//   LSTM: V0=Wih row, V1/V2=Whh row.    A1: V0/V1=tw1[:, :64] row.
//   trans: V0/V1=tw2 K-slice, V2[0..9]=Bz rows, V2[10..25]=w3 (wave4).
// ---------------------------------------------------------------------------
__global__ __launch_bounds__(512)
__attribute__((amdgpu_waves_per_eu(2, 2)))
void scan_kernel(
    const float* __restrict__ obs,
    const float* __restrict__ Wih,
    const float* __restrict__ Whh,
    const float* __restrict__ bih,
    const float* __restrict__ bhh,
    const float* __restrict__ tw1,
    const float* __restrict__ tb1,
    const float* __restrict__ tg,
    const float* __restrict__ tbeta,
    const float* __restrict__ tw2,
    const float* __restrict__ tb2,
    const float* __restrict__ tw3,
    const float* __restrict__ tb3,
    const float* __restrict__ z0m,
    const float* __restrict__ z0lv,
    float* __restrict__ out_tm,
    float* __restrict__ out_tlv)
{
    __shared__ __align__(16) float hring[8][64];
    __shared__ __align__(16) float oring[8][32];
    __shared__ __align__(16) float A1ring[8][128];
    __shared__ __align__(16) float h1w[2][64];
    __shared__ float p2s[64];
    __shared__ float z_s[8];
    __shared__ int hflag[4];
    __shared__ int aflag[2];
    __shared__ int p2flag;
    __shared__ int ttag;

    const int tid  = threadIdx.x;
    const int wid  = tid >> 6;
    const int lane = tid & 63;
    const int b    = blockIdx.x;

    vf32 V0, V1, V2;
    #pragma unroll
    for (int k = 0; k < 32; k++) { V0[k]=0.f; V1[k]=0.f; V2[k]=0.f; }

    float biasg = 0.f, b1r = 0.f, gr = 0.f, betar = 0.f, b2r = 0.f, b3r = 0.f;
    float c_st = 0.f, carry = 0.f;

    if (wid < 4) {
        const int g  = lane & 3;
        const int uu = wid*16 + (lane >> 2);
        const int row = g*64 + uu;
        biasg = bih[row] + bhh[row];
        #pragma unroll
        for (int k = 0; k < 32; k++) V0[k] = Wih[row*32 + k];
        #pragma unroll
        for (int k = 0; k < 32; k++) V1[k] = Whh[row*64 + k];
        #pragma unroll
        for (int k = 0; k < 32; k++) V2[k] = Whh[row*64 + 32 + k];
        if (g == 1 && uu < 32) carry = obs[((size_t)b*T_ + 4)*32 + uu];
    } else if (wid < 6) {
        const int ks = wid - 4;                      // K-slice / h1-half
        #pragma unroll
        for (int k = 0; k < 32; k++) V0[k] = tw2[lane*128 + ks*64 + k];
        #pragma unroll
        for (int k = 0; k < 32; k++) V1[k] = tw2[lane*128 + ks*64 + 32 + k];
        #pragma unroll
        for (int k = 0; k < 5; k++) {
            V2[k]     = tw1[lane*69 + 64 + k];        // Bz, row r0 = lane
            V2[5 + k] = tw1[(64 + lane)*69 + 64 + k]; // Bz, row r1 = 64+lane
        }
        const int r = ks*64 + lane;                  // own h1 row
        gr = tg[r]; betar = tbeta[r];
        if (ks == 0) {
            b2r = tb2[lane];
            if (lane < 40) {
                #pragma unroll
                for (int k = 0; k < 16; k++)
                    V2[10 + k] = tw3[(lane>>2)*64 + (lane&3)*16 + k];
                b3r = tb3[lane >> 2];
            }
        }
    } else {
        const int r = (wid - 6)*64 + lane;           // A1 row
        #pragma unroll
        for (int k = 0; k < 32; k++) V0[k] = tw1[r*69 + k];
        #pragma unroll
        for (int k = 0; k < 32; k++) V1[k] = tw1[r*69 + 32 + k];
        b1r = tb1[r];
    }

    // LDS / output init
    if (tid < 64) hring[7][tid] = 0.f;               // h(-1) at slot (-1)&7
    if (tid < 128) oring[tid >> 5][tid & 31] = obs[(size_t)b*T_*32 + tid]; // t=0..3
    if (tid < 5) {
        z_s[tid] = z0m[tid];
        out_tm [(size_t)b*T_*5 + tid] = z0m[tid];
        out_tlv[(size_t)b*T_*5 + tid] = z0lv[tid];
    }
    if (tid < 4) hflag[tid] = -1;
    if (tid < 2) aflag[tid] = 0;
    if (tid == 0) { p2flag = 0; ttag = 0; }
    __syncthreads();        // the ONLY workgroup barrier

    if (wid < 4) {
        // ======================= LSTM group =======================
        const int g  = lane & 3;
        const int uu = wid*16 + (lane >> 2);
        for (int t = 0; t < T_; ++t) {
            wait_ge(&hflag[0], t-1); wait_ge(&hflag[1], t-1);
            wait_ge(&hflag[2], t-1); wait_ge(&hflag[3], t-1);
            wait_ge(&aflag[0], t-8); wait_ge(&aflag[1], t-8);

            const float4* ob = (const float4*)oring[t & 7];
            const float4* hp = (const float4*)hring[(t - 1) & 7];
            float a0 = biasg, a1 = 0.f, a2 = 0.f, a3 = 0.f;
            #pragma unroll
            for (int k4 = 0; k4 < 8; k4++) {
                float4 o = ob[k4];
                a0 += V0[k4*4+0]*o.x;
                a1 += V0[k4*4+1]*o.y;
                a2 += V0[k4*4+2]*o.z;
                a3 += V0[k4*4+3]*o.w;
            }
            #pragma unroll
            for (int k4 = 0; k4 < 8; k4++) {
                float4 h = hp[k4];
                a0 += V1[k4*4+0]*h.x;
                a1 += V1[k4*4+1]*h.y;
                a2 += V1[k4*4+2]*h.z;
                a3 += V1[k4*4+3]*h.w;
            }
            #pragma unroll
            for (int k4 = 0; k4 < 8; k4++) {
                float4 h = hp[8 + k4];
                a0 += V2[k4*4+0]*h.x;
                a1 += V2[k4*4+1]*h.y;
                a2 += V2[k4*4+2]*h.z;
                a3 += V2[k4*4+3]*h.w;
            }
            const float G = (a0 + a1) + (a2 + a3);

            // quad all-gather (validated in R7)
            const float x1 = __shfl_xor(G, 1, 64);
            const float x2 = __shfl_xor(G, 2, 64);
            const float x3 = __shfl_xor(x1, 2, 64);
            const bool c1 = (g & 1), c2 = (g & 2);
            float iv = c2 ? (c1 ? x3 : x2) : (c1 ? x1 : G );
            float fv = c2 ? (c1 ? x2 : x3) : (c1 ? G  : x1);
            float gv = c2 ? (c1 ? x1 : G ) : (c1 ? x3 : x2);
            float ov = c2 ? (c1 ? G  : x1) : (c1 ? x2 : x3);

            iv = fast_sigmoid(iv);
            fv = fast_sigmoid(fv);
            gv = fast_tanh(gv);
            ov = fast_sigmoid(ov);
            c_st = fv*c_st + iv*gv;
            const float hv = ov * fast_tanh(c_st);

            if (g == 0) hring[t & 7][uu] = hv;
            if (g == 1 && uu < 32 && t + 4 < T_) oring[(t + 4) & 7][uu] = carry;
            st_rel(&hflag[wid], t);
            if (g == 1 && uu < 32 && t + 5 < T_)
                carry = obs[((size_t)b*T_ + t + 5)*32 + uu];
        }
    } else if (wid < 6) {
        // ======================= trans group (z-chain) =======================
        const int ks = wid - 4;
        for (int t = 1; t < T_; ++t) {
            wait_ge(&aflag[0], t); wait_ge(&aflag[1], t);
            wait_ge(&ttag, t - 1);

            const float z0 = z_s[0], z1 = z_s[1], z2 = z_s[2],
                        z3 = z_s[3], z4 = z_s[4];
            float a0 = A1ring[t & 7][lane]
                     + V2[0]*z0 + V2[1]*z1 + V2[2]*z2 + V2[3]*z3 + V2[4]*z4;
            float a1 = A1ring[t & 7][64 + lane]
                     + V2[5]*z0 + V2[6]*z1 + V2[7]*z2 + V2[8]*z3 + V2[9]*z4;
            // in-wave LN stats over all 128 rows (2 per lane)
            float s1 = a0 + a1, s2 = a0*a0 + a1*a1;
            #pragma unroll
            for (int m = 1; m < 64; m <<= 1) {
                s1 += __shfl_xor(s1, m, 64);
                s2 += __shfl_xor(s2, m, 64);
            }
            const float mean = s1 * (1.0f/128.0f);
            const float ms   = s2 * (1.0f/128.0f);
            const float var  = fmaxf(ms - mean*mean, 0.0f);
            const float rs   = rsqrtf(var + 1e-5f);
            const float aown = ks ? a1 : a0;
            const float h1v  = fast_tanh((aown - mean)*rs*gr + betar);

            h1w[ks][lane] = h1v;                     // wave-local strip
            __builtin_amdgcn_wave_barrier();

            // mv2 partial over own K-slice (weights in regs, h1 broadcast)
            float p0 = 0.f, p1 = 0.f, p2 = 0.f, p3 = 0.f;
            const float4* h4 = (const float4*)h1w[ks];
            #pragma unroll
            for (int k4 = 0; k4 < 8; k4++) {
                float4 h = h4[k4];
                p0 += V0[k4*4+0]*h.x;
                p1 += V0[k4*4+1]*h.y;
                p2 += V0[k4*4+2]*h.z;
                p3 += V0[k4*4+3]*h.w;
            }
            #pragma unroll
            for (int k4 = 0; k4 < 8; k4++) {
                float4 h = h4[8 + k4];
                p0 += V1[k4*4+0]*h.x;
                p1 += V1[k4*4+1]*h.y;
                p2 += V1[k4*4+2]*h.z;
                p3 += V1[k4*4+3]*h.w;
            }
            const float p = (p0 + p1) + (p2 + p3);

            if (ks == 1) {
                p2s[lane] = p;
                st_rel(&p2flag, t);
            } else {
                wait_ge(&p2flag, t);
                const float h2v = fast_tanh(b2r + p + p2s[lane]);
                const int pp = lane & 3;
                float acc = 0.f;
                #pragma unroll
                for (int k = 0; k < 16; k++)
                    acc += V2[10 + k] * __shfl(h2v, pp*16 + k, 64);
                acc += __shfl_xor(acc, 1, 64);
                acc += __shfl_xor(acc, 2, 64);
                if (pp == 0 && lane < 40) {
                    const int j = lane >> 2;         // 0..9
                    const float val = b3r + acc;
                    const size_t row = (size_t)b*T_ + t;
                    if (j < 5) {
                        z_s[j] = val;
                        out_tm[row*5 + j] = val;
                    } else {
                        out_tlv[row*5 + (j - 5)] = fminf(10.0f, fmaxf(-10.0f, val));
                    }
                }
                st_rel(&ttag, t);
            }
        }
    } else {
        // ======================= A1 producers =======================
        const int r = (wid - 6)*64 + lane;
        for (int t = 1; t < T_; ++t) {
            wait_ge(&hflag[0], t); wait_ge(&hflag[1], t);
            wait_ge(&hflag[2], t); wait_ge(&hflag[3], t);
            wait_ge(&ttag, t - 8);

            const float4* hv4 = (const float4*)hring[t & 7];
            float s0 = b1r, s1 = 0.f, s2 = 0.f, s3 = 0.f;
            #pragma unroll
            for (int k4 = 0; k4 < 8; k4++) {
                float4 h = hv4[k4];
                s0 += V0[k4*4+0]*h.x;
                s1 += V0[k4*4+1]*h.y;
                s2 += V0[k4*4+2]*h.z;
                s3 += V0[k4*4+3]*h.w;
            }
            #pragma unroll
            for (int k4 = 0; k4 < 8; k4++) {
                float4 h = hv4[8 + k4];
                s0 += V1[k4*4+0]*h.x;
                s1 += V1[k4*4+1]*h.y;
                s2 += V1[k4*4+2]*h.z;
                s3 += V1[k4*4+3]*h.w;
            }
            A1ring[t & 7][r] = (s0 + s1) + (s2 + s3);
            st_rel(&aflag[wid - 6], t);
        }
    }
}

// ---------------------------------------------------------------------------
// Observation decoder (unchanged, ~435us): one wave per row; weights in LDS;
// h1/h2 staged per-wave, broadcast float4 re-reads; 4-way split accumulators.
// ---------------------------------------------------------------------------
#define DEC_BLOCKS 512

__global__ __launch_bounds__(512) void dec_kernel(
    const float* __restrict__ ow1,
    const float* __restrict__ ob1,
    const float* __restrict__ og,
    const float* __restrict__ obeta,
    const float* __restrict__ ow2,
    const float* __restrict__ ob2,
    const float* __restrict__ ow3,
    const float* __restrict__ ob3,
    const float* __restrict__ tmeans,
    float* __restrict__ out_om,
    float* __restrict__ out_olv)
{
    __shared__ float w1s[640];
    __shared__ float b1s[128], gs[128], bes[128];
    __shared__ float w2s[8192];
    __shared__ float b2s[64];
    __shared__ float w3s[4096];
    __shared__ float b3s[64];
    __shared__ __align__(16) float h1s[8][128];
    __shared__ __align__(16) float h2s[8][64];

    const int tid = threadIdx.x;
    for (int idx = tid; idx < 640; idx += 512) w1s[idx] = ow1[idx];
    for (int idx = tid; idx < 128; idx += 512) {
        b1s[idx] = ob1[idx]; gs[idx] = og[idx]; bes[idx] = obeta[idx];
    }
    for (int idx = tid; idx < 8192; idx += 512) {
        int k = idx >> 6, j = idx & 63;
        w2s[idx] = ow2[j*128 + k];
    }
    for (int idx = tid; idx < 4096; idx += 512) {
        int k = idx >> 6, j = idx & 63;
        w3s[idx] = ow3[j*64 + k];
    }
    for (int idx = tid; idx < 64; idx += 512) { b2s[idx] = ob2[idx]; b3s[idx] = ob3[idx]; }
    __syncthreads();

    const int lane   = tid & 63;
    const int wv     = tid >> 6;
    const int gwave  = (blockIdx.x * 512 + tid) >> 6;
    const int nwaves = DEC_BLOCKS * 8;
    const int j0 = lane, j1 = lane + 64;

    for (int row = gwave; row < B_*T_; row += nwaves) {
        const float z0v = tmeans[(size_t)row*5 + 0];
        const float z1v = tmeans[(size_t)row*5 + 1];
        const float z2v = tmeans[(size_t)row*5 + 2];
        const float z3v = tmeans[(size_t)row*5 + 3];
        const float z4v = tmeans[(size_t)row*5 + 4];

        float a = b1s[j0] + w1s[j0*5+0]*z0v + w1s[j0*5+1]*z1v + w1s[j0*5+2]*z2v
                + w1s[j0*5+3]*z3v + w1s[j0*5+4]*z4v;
        float bb = b1s[j1] + w1s[j1*5+0]*z0v + w1s[j1*5+1]*z1v + w1s[j1*5+2]*z2v
                 + w1s[j1*5+3]*z3v + w1s[j1*5+4]*z4v;
        float s1 = a + bb, s2 = a*a + bb*bb;
        #pragma unroll
        for (int m = 1; m < 64; m <<= 1) {
            s1 += __shfl_xor(s1, m, 64);
            s2 += __shfl_xor(s2, m, 64);
        }
        const float mean = s1 * (1.0f/128.0f);
        const float var  = fmaxf(s2 * (1.0f/128.0f) - mean*mean, 0.0f);
        const float rs   = rsqrtf(var + 1e-5f);
        const float h1a  = fast_tanh((a  - mean)*rs*gs[j0] + bes[j0]);
        const float h1b  = fast_tanh((bb - mean)*rs*gs[j1] + bes[j1]);

        h1s[wv][lane]      = h1a;
        h1s[wv][64 + lane] = h1b;
        __builtin_amdgcn_wave_barrier();

        float acc2a = b2s[lane], acc2b = 0.f, acc2c = 0.f, acc2d = 0.f;
        const float4* h14 = (const float4*)(h1s[wv]);
        #pragma unroll
        for (int k4 = 0; k4 < 32; k4++) {
            float4 h = h14[k4];
            acc2a += h.x * w2s[(k4*4+0)*64 + lane];
            acc2b += h.y * w2s[(k4*4+1)*64 + lane];
            acc2c += h.z * w2s[(k4*4+2)*64 + lane];
            acc2d += h.w * w2s[(k4*4+3)*64 + lane];
        }
        const float h2v = fast_tanh(acc2a + acc2b + acc2c + acc2d);

        h2s[wv][lane] = h2v;
        __builtin_amdgcn_wave_barrier();

        float acc3a = b3s[lane], acc3b = 0.f, acc3c = 0.f, acc3d = 0.f;
        const float4* h24 = (const float4*)(h2s[wv]);
        #pragma unroll
        for (int k4 = 0; k4 < 16; k4++) {
            float4 h = h24[k4];
            acc3a += h.x * w3s[(k4*4+0)*64 + lane];
            acc3b += h.y * w3s[(k4*4+1)*64 + lane];
            acc3c += h.z * w3s[(k4*4+2)*64 + lane];
            acc3d += h.w * w3s[(k4*4+3)*64 + lane];
        }
        const float acc3 = acc3a + acc3b + acc3c + acc3d;

        if (lane < 32) {
            out_om[(size_t)row*32 + lane] = acc3;
        } else {
            out_olv[(size_t)row*32 + (lane - 32)] = fminf(10.0f, fmaxf(-10.0f, acc3));
        }
    }
}

extern "C" void kernel_launch(void* const* d_in, const int* in_sizes, int n_in,
                              void* d_out, int out_size, void* d_ws, size_t ws_size,
                              hipStream_t stream) {
    const float* obs  = (const float*)d_in[0];
    const float* Wih  = (const float*)d_in[1];
    const float* Whh  = (const float*)d_in[2];
    const float* bih  = (const float*)d_in[3];
    const float* bhh  = (const float*)d_in[4];
    const float* tw1  = (const float*)d_in[5];
    const float* tb1  = (const float*)d_in[6];
    const float* tg   = (const float*)d_in[7];
    const float* tbe  = (const float*)d_in[8];
    const float* tw2  = (const float*)d_in[9];
    const float* tb2  = (const float*)d_in[10];
    const float* tw3  = (const float*)d_in[11];
    const float* tb3  = (const float*)d_in[12];
    const float* ow1  = (const float*)d_in[13];
    const float* ob1  = (const float*)d_in[14];
    const float* og   = (const float*)d_in[15];
    const float* obe  = (const float*)d_in[16];
    const float* ow2  = (const float*)d_in[17];
    const float* ob2  = (const float*)d_in[18];
    const float* ow3  = (const float*)d_in[19];
    const float* ob3  = (const float*)d_in[20];
    const float* z0m  = (const float*)d_in[21];
    const float* z0lv = (const float*)d_in[22];

    float* out0 = (float*)d_out;                   // obs_means   (B,T,32)
    float* out1 = out0 + (size_t)B_*T_*32;         // obs_logvars (B,T,32)
    float* out2 = out1 + (size_t)B_*T_*32;         // trans_means (B,T,5)
    float* out3 = out2 + (size_t)B_*T_*5;          // trans_logvars

    scan_kernel<<<B_, 512, 0, stream>>>(obs, Wih, Whh, bih, bhh,
                                        tw1, tb1, tg, tbe, tw2, tb2, tw3, tb3,
                                        z0m, z0lv, out2, out3);

    dec_kernel<<<DEC_BLOCKS, 512, 0, stream>>>(
        ow1, ob1, og, obe, ow2, ob2, ow3, ob3, out2, out0, out1);
}

// Round 9
// 2758.698 us; speedup vs baseline: 1.9148x; 1.1366x over previous
//
#include <hip/hip_runtime.h>

#define B_ 128
#define T_ 2048

typedef float vf32 __attribute__((ext_vector_type(32)));

__device__ __forceinline__ float fast_sigmoid(float x){
    return 1.0f / (1.0f + __expf(-x));
}
__device__ __forceinline__ float fast_tanh(float x){
    float a = fabsf(x);
    float e = __expf(2.0f*a);
    float r = 1.0f - 2.0f/(e + 1.0f);   // e=inf -> r=1, no NaN
    return (x < 0.0f) ? -r : r;
}

// ---- VALU cross-lane helpers (replace LDS-pipe shfl, ~120cy -> ~10cy) ----
// quad_perm encodings: xor1=0xB1 [1,0,3,2], xor2=0x4E [2,3,0,1],
// xor3=0x1B [3,2,1,0]; row_half_mirror=0x141 (pairs quads within 8),
// row_mirror=0x140 (pairs 8s within 16).
template<int CTRL>
__device__ __forceinline__ float dpp_mov(float x){
    return __int_as_float(__builtin_amdgcn_update_dpp(
        0, __float_as_int(x), CTRL, 0xF, 0xF, true));
}

// Full 64-lane sum, all lanes get the total.  Stages 1,2,4,8 via DPP
// (VALU).  Stages 16,32 via gfx950 permlane*_swap when available: with both
// operands = v, the two results are the {lo,lo} and {hi,hi} halves in SOME
// order, so r[0]+r[1] is the cross-half sum in every lane regardless of the
// swap direction (direction-proof).  Fallback: shfl_xor (ds pipe).
__device__ __forceinline__ float wave_sum64(float v){
    v += dpp_mov<0xB1>(v);
    v += dpp_mov<0x4E>(v);
    v += dpp_mov<0x141>(v);
    v += dpp_mov<0x140>(v);
#if __has_builtin(__builtin_amdgcn_permlane16_swap)
    {
        auto r = __builtin_amdgcn_permlane16_swap(__float_as_int(v),
                                                  __float_as_int(v), false, false);
        v = __int_as_float(r[0]) + __int_as_float(r[1]);
    }
#else
    v += __shfl_xor(v, 16, 64);
#endif
#if __has_builtin(__builtin_amdgcn_permlane32_swap)
    {
        auto r = __builtin_amdgcn_permlane32_swap(__float_as_int(v),
                                                  __float_as_int(v), false, false);
        v = __int_as_float(r[0]) + __int_as_float(r[1]);
    }
#else
    v += __shfl_xor(v, 32, 64);
#endif
    return v;
}

// LDS flag sync helpers (workgroup scope, acquire/release) -- R6-validated
__device__ __forceinline__ void wait_ge(int* p, int v){
    while (__hip_atomic_load(p, __ATOMIC_ACQUIRE, __HIP_MEMORY_SCOPE_WORKGROUP) < v) { }
}
__device__ __forceinline__ void st_rel(int* p, int v){
    __hip_atomic_store(p, v, __ATOMIC_RELEASE, __HIP_MEMORY_SCOPE_WORKGROUP);
}

// ---------------------------------------------------------------------------
// Merged scan (R8 structure, z-chain de-LDS'd).  R8 measured 1.34us/step with
// the z-chain as pacer; chain budget showed ~2/3 of it was cross-lane ops on
// the LDS pipe (butterfly 12 serial ds_swizzle ~700cy, mv3 tail ~240cy,
// ttag+z_s handoff ~400cy).  This round: DPP/permlane reductions (VALU),
// symmetric redundant finish in waves 4/5 (no p2flag serialization, z kept
// in registers + in-wave broadcast), parity-double-buffered p2s.
//
//   waves 0-3: quad-gate LSTM.  Lane 4u+g owns gate row g*64+(wid*16+u);
//     gates gathered via 3 DPP quad_perms (no LDS).  h(t) -> hring(8).
//   waves 6-7: A1 producers: A1[t] = tb1 + tw1[:, :64].h(t) -> A1ring(8).
//   waves 4-5: z-chain, symmetric: both compute mv1(2 rows/lane)+LN(DPP)+
//     own h1 half -> wave-local strip -> mv2 K-split -> exchange partials
//     (parity p2s + pf flags) -> BOTH compute h2, mv3, z; z broadcast
//     in-wave via 5 pipelined shfls (overlaps next aflag wait).  wave4
//     writes outputs + ttag (A1 ring back-pressure only).
//
// Deadlock-freedom: LSTM waits hflag(t-1), aflag(t-8); A1 waits hflag(t),
// ttag(t-8); wave4 waits aflag(t), pf[1](t); wave5 waits aflag(t), pf[0](t).
// pf-induction also proves the parity p2s buffers are never overwritten
// before the partner's read (wave5 reaching step t+2's write requires
// pf[0]>=t+1, which wave4 sets only after completing step t's reads).
// Register roles (union V0..V2, 96 slots max -- R3 invariant):
//   LSTM: V0=Wih row, V1/V2=Whh row.   A1: V0/V1=tw1[:, :64] row.
//   trans: V0/V1=tw2 K-slice(64), V2[0..9]=Bz rows, V2[10..25]=w3 (90 used).
// ---------------------------------------------------------------------------
__global__ __launch_bounds__(512)
__attribute__((amdgpu_waves_per_eu(2, 2)))
void scan_kernel(
    const float* __restrict__ obs,
    const float* __restrict__ Wih,
    const float* __restrict__ Whh,
    const float* __restrict__ bih,
    const float* __restrict__ bhh,
    const float* __restrict__ tw1,
    const float* __restrict__ tb1,
    const float* __restrict__ tg,
    const float* __restrict__ tbeta,
    const float* __restrict__ tw2,
    const float* __restrict__ tb2,
    const float* __restrict__ tw3,
    const float* __restrict__ tb3,
    const float* __restrict__ z0m,
    const float* __restrict__ z0lv,
    float* __restrict__ out_tm,
    float* __restrict__ out_tlv)
{
    __shared__ __align__(16) float hring[8][64];
    __shared__ __align__(16) float oring[8][32];
    __shared__ __align__(16) float A1ring[8][128];
    __shared__ __align__(16) float h1w[2][64];
    __shared__ float p2s[2][2][64];      // [t&1][wave][lane]
    __shared__ int hflag[4];
    __shared__ int aflag[2];
    __shared__ int pf[2];
    __shared__ int ttag;

    const int tid  = threadIdx.x;
    const int wid  = tid >> 6;
    const int lane = tid & 63;
    const int b    = blockIdx.x;

    vf32 V0, V1, V2;
    #pragma unroll
    for (int k = 0; k < 32; k++) { V0[k]=0.f; V1[k]=0.f; V2[k]=0.f; }

    float biasg = 0.f, b1r = 0.f, gr = 0.f, betar = 0.f, b2r = 0.f, b3r = 0.f;
    float c_st = 0.f, carry = 0.f;

    if (wid < 4) {
        const int g  = lane & 3;
        const int uu = wid*16 + (lane >> 2);
        const int row = g*64 + uu;
        biasg = bih[row] + bhh[row];
        #pragma unroll
        for (int k = 0; k < 32; k++) V0[k] = Wih[row*32 + k];
        #pragma unroll
        for (int k = 0; k < 32; k++) V1[k] = Whh[row*64 + k];
        #pragma unroll
        for (int k = 0; k < 32; k++) V2[k] = Whh[row*64 + 32 + k];
        if (g == 1 && uu < 32) carry = obs[((size_t)b*T_ + 4)*32 + uu];
    } else if (wid < 6) {
        const int ks = wid - 4;                      // K-slice / h1-half
        #pragma unroll
        for (int k = 0; k < 32; k++) V0[k] = tw2[lane*128 + ks*64 + k];
        #pragma unroll
        for (int k = 0; k < 32; k++) V1[k] = tw2[lane*128 + ks*64 + 32 + k];
        #pragma unroll
        for (int k = 0; k < 5; k++) {
            V2[k]     = tw1[lane*69 + 64 + k];        // Bz, row r0 = lane
            V2[5 + k] = tw1[(64 + lane)*69 + 64 + k]; // Bz, row r1 = 64+lane
        }
        const int r = ks*64 + lane;                  // own h1 row
        gr = tg[r]; betar = tbeta[r];
        b2r = tb2[lane];                             // both waves (symmetric)
        if (lane < 40) {
            #pragma unroll
            for (int k = 0; k < 16; k++)
                V2[10 + k] = tw3[(lane>>2)*64 + (lane&3)*16 + k];
            b3r = tb3[lane >> 2];
        }
    } else {
        const int r = (wid - 6)*64 + lane;           // A1 row
        #pragma unroll
        for (int k = 0; k < 32; k++) V0[k] = tw1[r*69 + k];
        #pragma unroll
        for (int k = 0; k < 32; k++) V1[k] = tw1[r*69 + 32 + k];
        b1r = tb1[r];
    }

    // LDS / output init
    if (tid < 64) hring[7][tid] = 0.f;               // h(-1) at slot (-1)&7
    if (tid < 128) oring[tid >> 5][tid & 31] = obs[(size_t)b*T_*32 + tid]; // t=0..3
    if (tid < 5) {
        out_tm [(size_t)b*T_*5 + tid] = z0m[tid];
        out_tlv[(size_t)b*T_*5 + tid] = z0lv[tid];
    }
    if (tid < 4) hflag[tid] = -1;
    if (tid < 2) { aflag[tid] = 0; pf[tid] = 0; }
    if (tid == 0) ttag = 0;
    __syncthreads();        // the ONLY workgroup barrier

    if (wid < 4) {
        // ======================= LSTM group =======================
        const int g  = lane & 3;
        const int uu = wid*16 + (lane >> 2);
        for (int t = 0; t < T_; ++t) {
            wait_ge(&hflag[0], t-1); wait_ge(&hflag[1], t-1);
            wait_ge(&hflag[2], t-1); wait_ge(&hflag[3], t-1);
            wait_ge(&aflag[0], t-8); wait_ge(&aflag[1], t-8);

            const float4* ob = (const float4*)oring[t & 7];
            const float4* hp = (const float4*)hring[(t - 1) & 7];
            float a0 = biasg, a1 = 0.f, a2 = 0.f, a3 = 0.f;
            #pragma unroll
            for (int k4 = 0; k4 < 8; k4++) {
                float4 o = ob[k4];
                a0 += V0[k4*4+0]*o.x;
                a1 += V0[k4*4+1]*o.y;
                a2 += V0[k4*4+2]*o.z;
                a3 += V0[k4*4+3]*o.w;
            }
            #pragma unroll
            for (int k4 = 0; k4 < 8; k4++) {
                float4 h = hp[k4];
                a0 += V1[k4*4+0]*h.x;
                a1 += V1[k4*4+1]*h.y;
                a2 += V1[k4*4+2]*h.z;
                a3 += V1[k4*4+3]*h.w;
            }
            #pragma unroll
            for (int k4 = 0; k4 < 8; k4++) {
                float4 h = hp[8 + k4];
                a0 += V2[k4*4+0]*h.x;
                a1 += V2[k4*4+1]*h.y;
                a2 += V2[k4*4+2]*h.z;
                a3 += V2[k4*4+3]*h.w;
            }
            const float G = (a0 + a1) + (a2 + a3);

            // quad all-gather via DPP (was 3 shfl_xor on the LDS pipe)
            const float x1 = dpp_mov<0xB1>(G);   // lane^1
            const float x2 = dpp_mov<0x4E>(G);   // lane^2
            const float x3 = dpp_mov<0x1B>(G);   // lane^3
            const bool c1 = (g & 1), c2 = (g & 2);
            float iv = c2 ? (c1 ? x3 : x2) : (c1 ? x1 : G );
            float fv = c2 ? (c1 ? x2 : x3) : (c1 ? G  : x1);
            float gv = c2 ? (c1 ? x1 : G ) : (c1 ? x3 : x2);
            float ov = c2 ? (c1 ? G  : x1) : (c1 ? x2 : x3);

            iv = fast_sigmoid(iv);
            fv = fast_sigmoid(fv);
            gv = fast_tanh(gv);
            ov = fast_sigmoid(ov);
            c_st = fv*c_st + iv*gv;
            const float hv = ov * fast_tanh(c_st);

            if (g == 0) hring[t & 7][uu] = hv;
            if (g == 1 && uu < 32 && t + 4 < T_) oring[(t + 4) & 7][uu] = carry;
            st_rel(&hflag[wid], t);
            if (g == 1 && uu < 32 && t + 5 < T_)
                carry = obs[((size_t)b*T_ + t + 5)*32 + uu];
        }
    } else if (wid < 6) {
        // =============== trans group (symmetric z-chain) ===============
        const int ks = wid - 4;
        float zr0 = z0m[0], zr1 = z0m[1], zr2 = z0m[2],
              zr3 = z0m[3], zr4 = z0m[4];
        for (int t = 1; t < T_; ++t) {
            wait_ge(&aflag[0], t); wait_ge(&aflag[1], t);

            // mv1: 2 rows/lane; z from registers (broadcast last step)
            float a0 = A1ring[t & 7][lane]
                     + V2[0]*zr0 + V2[1]*zr1 + V2[2]*zr2 + V2[3]*zr3 + V2[4]*zr4;
            float a1 = A1ring[t & 7][64 + lane]
                     + V2[5]*zr0 + V2[6]*zr1 + V2[7]*zr2 + V2[8]*zr3 + V2[9]*zr4;
            // LN stats over 128 rows via VALU reduction (was 12 ds stages)
            const float s1 = wave_sum64(a0 + a1);
            const float s2 = wave_sum64(a0*a0 + a1*a1);
            const float mean = s1 * (1.0f/128.0f);
            const float var  = fmaxf(s2 * (1.0f/128.0f) - mean*mean, 0.0f);
            const float rs   = rsqrtf(var + 1e-5f);
            const float aown = ks ? a1 : a0;
            const float h1v  = fast_tanh((aown - mean)*rs*gr + betar);

            h1w[ks][lane] = h1v;                     // wave-local strip
            __builtin_amdgcn_wave_barrier();

            // mv2 partial over own K-slice
            float p0 = 0.f, p1 = 0.f, p2 = 0.f, p3 = 0.f;
            const float4* h4 = (const float4*)h1w[ks];
            #pragma unroll
            for (int k4 = 0; k4 < 8; k4++) {
                float4 h = h4[k4];
                p0 += V0[k4*4+0]*h.x;
                p1 += V0[k4*4+1]*h.y;
                p2 += V0[k4*4+2]*h.z;
                p3 += V0[k4*4+3]*h.w;
            }
            #pragma unroll
            for (int k4 = 0; k4 < 8; k4++) {
                float4 h = h4[8 + k4];
                p0 += V1[k4*4+0]*h.x;
                p1 += V1[k4*4+1]*h.y;
                p2 += V1[k4*4+2]*h.z;
                p3 += V1[k4*4+3]*h.w;
            }
            const float p = (p0 + p1) + (p2 + p3);

            // exchange partials (parity buffer; both waves proceed)
            p2s[t & 1][ks][lane] = p;
            st_rel(&pf[ks], t);
            wait_ge(&pf[ks ^ 1], t);
            const float pother = p2s[t & 1][ks ^ 1][lane];

            // BOTH waves: h2, mv3, z (redundant; kills the finisher hop)
            const float h2v = fast_tanh(b2r + p + pother);
            const int pp = lane & 3;
            float ac0 = 0.f, ac1 = 0.f, ac2 = 0.f, ac3 = 0.f;
            #pragma unroll
            for (int k = 0; k < 4; k++) {
                ac0 += V2[10 + k]      * __shfl(h2v, pp*16 + k,      64);
                ac1 += V2[10 + 4 + k]  * __shfl(h2v, pp*16 + 4 + k,  64);
                ac2 += V2[10 + 8 + k]  * __shfl(h2v, pp*16 + 8 + k,  64);
                ac3 += V2[10 + 12 + k] * __shfl(h2v, pp*16 + 12 + k, 64);
            }
            float acc = (ac0 + ac1) + (ac2 + ac3);
            acc += dpp_mov<0xB1>(acc);
            acc += dpp_mov<0x4E>(acc);       // lanes 4j..4j+3 hold row-j total
            const float val = b3r + acc;

            if (ks == 0) {
                if (pp == 0 && lane < 40) {
                    const int j = lane >> 2;          // 0..9
                    const size_t row = (size_t)b*T_ + t;
                    if (j < 5) out_tm[row*5 + j] = val;
                    else out_tlv[row*5 + (j - 5)] =
                             fminf(10.0f, fmaxf(-10.0f, val));
                }
                st_rel(&ttag, t);        // A1 ring back-pressure only
            }
            // in-wave z broadcast for next step (z_j lives in lane 4j)
            zr0 = __shfl(val, 0, 64);
            zr1 = __shfl(val, 4, 64);
            zr2 = __shfl(val, 8, 64);
            zr3 = __shfl(val, 12, 64);
            zr4 = __shfl(val, 16, 64);
        }
    } else {
        // ======================= A1 producers =======================
        const int r = (wid - 6)*64 + lane;
        for (int t = 1; t < T_; ++t) {
            wait_ge(&hflag[0], t); wait_ge(&hflag[1], t);
            wait_ge(&hflag[2], t); wait_ge(&hflag[3], t);
            wait_ge(&ttag, t - 8);

            const float4* hv4 = (const float4*)hring[t & 7];
            float s0 = b1r, s1 = 0.f, s2 = 0.f, s3 = 0.f;
            #pragma unroll
            for (int k4 = 0; k4 < 8; k4++) {
                float4 h = hv4[k4];
                s0 += V0[k4*4+0]*h.x;
                s1 += V0[k4*4+1]*h.y;
                s2 += V0[k4*4+2]*h.z;
                s3 += V0[k4*4+3]*h.w;
            }
            #pragma unroll
            for (int k4 = 0; k4 < 8; k4++) {
                float4 h = hv4[8 + k4];
                s0 += V1[k4*4+0]*h.x;
                s1 += V1[k4*4+1]*h.y;
                s2 += V1[k4*4+2]*h.z;
                s3 += V1[k4*4+3]*h.w;
            }
            A1ring[t & 7][r] = (s0 + s1) + (s2 + s3);
            st_rel(&aflag[wid - 6], t);
        }
    }
}

// ---------------------------------------------------------------------------
// Observation decoder: butterfly moved to DPP/permlane (offloads the DS pipe,
// which this kernel saturates with weight reads); otherwise unchanged.
// ---------------------------------------------------------------------------
#define DEC_BLOCKS 512

__global__ __launch_bounds__(512) void dec_kernel(
    const float* __restrict__ ow1,
    const float* __restrict__ ob1,
    const float* __restrict__ og,
    const float* __restrict__ obeta,
    const float* __restrict__ ow2,
    const float* __restrict__ ob2,
    const float* __restrict__ ow3,
    const float* __restrict__ ob3,
    const float* __restrict__ tmeans,
    float* __restrict__ out_om,
    float* __restrict__ out_olv)
{
    __shared__ float w1s[640];
    __shared__ float b1s[128], gs[128], bes[128];
    __shared__ float w2s[8192];
    __shared__ float b2s[64];
    __shared__ float w3s[4096];
    __shared__ float b3s[64];
    __shared__ __align__(16) float h1s[8][128];
    __shared__ __align__(16) float h2s[8][64];

    const int tid = threadIdx.x;
    for (int idx = tid; idx < 640; idx += 512) w1s[idx] = ow1[idx];
    for (int idx = tid; idx < 128; idx += 512) {
        b1s[idx] = ob1[idx]; gs[idx] = og[idx]; bes[idx] = obeta[idx];
    }
    for (int idx = tid; idx < 8192; idx += 512) {
        int k = idx >> 6, j = idx & 63;
        w2s[idx] = ow2[j*128 + k];
    }
    for (int idx = tid; idx < 4096; idx += 512) {
        int k = idx >> 6, j = idx & 63;
        w3s[idx] = ow3[j*64 + k];
    }
    for (int idx = tid; idx < 64; idx += 512) { b2s[idx] = ob2[idx]; b3s[idx] = ob3[idx]; }
    __syncthreads();

    const int lane   = tid & 63;
    const int wv     = tid >> 6;
    const int gwave  = (blockIdx.x * 512 + tid) >> 6;
    const int nwaves = DEC_BLOCKS * 8;
    const int j0 = lane, j1 = lane + 64;

    for (int row = gwave; row < B_*T_; row += nwaves) {
        const float z0v = tmeans[(size_t)row*5 + 0];
        const float z1v = tmeans[(size_t)row*5 + 1];
        const float z2v = tmeans[(size_t)row*5 + 2];
        const float z3v = tmeans[(size_t)row*5 + 3];
        const float z4v = tmeans[(size_t)row*5 + 4];

        float a = b1s[j0] + w1s[j0*5+0]*z0v + w1s[j0*5+1]*z1v + w1s[j0*5+2]*z2v
                + w1s[j0*5+3]*z3v + w1s[j0*5+4]*z4v;
        float bb = b1s[j1] + w1s[j1*5+0]*z0v + w1s[j1*5+1]*z1v + w1s[j1*5+2]*z2v
                 + w1s[j1*5+3]*z3v + w1s[j1*5+4]*z4v;
        const float s1 = wave_sum64(a + bb);
        const float s2 = wave_sum64(a*a + bb*bb);
        const float mean = s1 * (1.0f/128.0f);
        const float var  = fmaxf(s2 * (1.0f/128.0f) - mean*mean, 0.0f);
        const float rs   = rsqrtf(var + 1e-5f);
        const float h1a  = fast_tanh((a  - mean)*rs*gs[j0] + bes[j0]);
        const float h1b  = fast_tanh((bb - mean)*rs*gs[j1] + bes[j1]);

        h1s[wv][lane]      = h1a;
        h1s[wv][64 + lane] = h1b;
        __builtin_amdgcn_wave_barrier();

        float acc2a = b2s[lane], acc2b = 0.f, acc2c = 0.f, acc2d = 0.f;
        const float4* h14 = (const float4*)(h1s[wv]);
        #pragma unroll
        for (int k4 = 0; k4 < 32; k4++) {
            float4 h = h14[k4];
            acc2a += h.x * w2s[(k4*4+0)*64 + lane];
            acc2b += h.y * w2s[(k4*4+1)*64 + lane];
            acc2c += h.z * w2s[(k4*4+2)*64 + lane];
            acc2d += h.w * w2s[(k4*4+3)*64 + lane];
        }
        const float h2v = fast_tanh(acc2a + acc2b + acc2c + acc2d);

        h2s[wv][lane] = h2v;
        __builtin_amdgcn_wave_barrier();

        float acc3a = b3s[lane], acc3b = 0.f, acc3c = 0.f, acc3d = 0.f;
        const float4* h24 = (const float4*)(h2s[wv]);
        #pragma unroll
        for (int k4 = 0; k4 < 16; k4++) {
            float4 h = h24[k4];
            acc3a += h.x * w3s[(k4*4+0)*64 + lane];
            acc3b += h.y * w3s[(k4*4+1)*64 + lane];
            acc3c += h.z * w3s[(k4*4+2)*64 + lane];
            acc3d += h.w * w3s[(k4*4+3)*64 + lane];
        }
        const float acc3 = acc3a + acc3b + acc3c + acc3d;

        if (lane < 32) {
            out_om[(size_t)row*32 + lane] = acc3;
        } else {
            out_olv[(size_t)row*32 + (lane - 32)] = fminf(10.0f, fmaxf(-10.0f, acc3));
        }
    }
}

extern "C" void kernel_launch(void* const* d_in, const int* in_sizes, int n_in,
                              void* d_out, int out_size, void* d_ws, size_t ws_size,
                              hipStream_t stream) {
    const float* obs  = (const float*)d_in[0];
    const float* Wih  = (const float*)d_in[1];
    const float* Whh  = (const float*)d_in[2];
    const float* bih  = (const float*)d_in[3];
    const float* bhh  = (const float*)d_in[4];
    const float* tw1  = (const float*)d_in[5];
    const float* tb1  = (const float*)d_in[6];
    const float* tg   = (const float*)d_in[7];
    const float* tbe  = (const float*)d_in[8];
    const float* tw2  = (const float*)d_in[9];
    const float* tb2  = (const float*)d_in[10];
    const float* tw3  = (const float*)d_in[11];
    const float* tb3  = (const float*)d_in[12];
    const float* ow1  = (const float*)d_in[13];
    const float* ob1  = (const float*)d_in[14];
    const float* og   = (const float*)d_in[15];
    const float* obe  = (const float*)d_in[16];
    const float* ow2  = (const float*)d_in[17];
    const float* ob2  = (const float*)d_in[18];
    const float* ow3  = (const float*)d_in[19];
    const float* ob3  = (const float*)d_in[20];
    const float* z0m  = (const float*)d_in[21];
    const float* z0lv = (const float*)d_in[22];

    float* out0 = (float*)d_out;                   // obs_means   (B,T,32)
    float* out1 = out0 + (size_t)B_*T_*32;         // obs_logvars (B,T,32)
    float* out2 = out1 + (size_t)B_*T_*32;         // trans_means (B,T,5)
    float* out3 = out2 + (size_t)B_*T_*5;          // trans_logvars

    scan_kernel<<<B_, 512, 0, stream>>>(obs, Wih, Whh, bih, bhh,
                                        tw1, tb1, tg, tbe, tw2, tb2, tw3, tb3,
                                        z0m, z0lv, out2, out3);

    dec_kernel<<<DEC_BLOCKS, 512, 0, stream>>>(
        ow1, ob1, og, obe, ow2, ob2, ow3, ob3, out2, out0, out1);
}

// Round 10
// 2753.632 us; speedup vs baseline: 1.9183x; 1.0018x over previous
//
#include <hip/hip_runtime.h>

#define B_ 128
#define T_ 2048

typedef float vf32 __attribute__((ext_vector_type(32)));

__device__ __forceinline__ float fast_sigmoid(float x){
    return 1.0f / (1.0f + __expf(-x));
}
__device__ __forceinline__ float fast_tanh(float x){
    float a = fabsf(x);
    float e = __expf(2.0f*a);
    float r = 1.0f - 2.0f/(e + 1.0f);   // e=inf -> r=1, no NaN
    return (x < 0.0f) ? -r : r;
}

// ---- VALU cross-lane helpers ----
template<int CTRL>
__device__ __forceinline__ float dpp_mov(float x){
    return __int_as_float(__builtin_amdgcn_update_dpp(
        0, __float_as_int(x), CTRL, 0xF, 0xF, true));
}

// Full 64-lane sum on the VALU pipe (R9-validated).
__device__ __forceinline__ float wave_sum64(float v){
    v += dpp_mov<0xB1>(v);
    v += dpp_mov<0x4E>(v);
    v += dpp_mov<0x141>(v);
    v += dpp_mov<0x140>(v);
#if __has_builtin(__builtin_amdgcn_permlane16_swap)
    {
        auto r = __builtin_amdgcn_permlane16_swap(__float_as_int(v),
                                                  __float_as_int(v), false, false);
        v = __int_as_float(r[0]) + __int_as_float(r[1]);
    }
#else
    v += __shfl_xor(v, 16, 64);
#endif
#if __has_builtin(__builtin_amdgcn_permlane32_swap)
    {
        auto r = __builtin_amdgcn_permlane32_swap(__float_as_int(v),
                                                  __float_as_int(v), false, false);
        v = __int_as_float(r[0]) + __int_as_float(r[1]);
    }
#else
    v += __shfl_xor(v, 32, 64);
#endif
    return v;
}

__device__ __forceinline__ float readlane_f(float v, int l){
    return __int_as_float(__builtin_amdgcn_readlane(__float_as_int(v), l));
}

// LDS flag sync (workgroup scope, acquire/release).
// Tight spin: latency-critical consumer waits.
__device__ __forceinline__ void wait_ge(int* p, int v){
    while (__hip_atomic_load(p, __ATOMIC_ACQUIRE, __HIP_MEMORY_SCOPE_WORKGROUP) < v) { }
}
// Backoff spin: ahead-running waves (ring back-pressure) -- don't hammer the
// LDS pipe that productive co-scheduled waves need.
__device__ __forceinline__ void wait_ge_slp(int* p, int v){
    while (__hip_atomic_load(p, __ATOMIC_ACQUIRE, __HIP_MEMORY_SCOPE_WORKGROUP) < v)
        __builtin_amdgcn_s_sleep(1);
}
__device__ __forceinline__ void st_rel(int* p, int v){
    __hip_atomic_store(p, v, __ATOMIC_RELEASE, __HIP_MEMORY_SCOPE_WORKGROUP);
}

// ---------------------------------------------------------------------------
// Merged scan (R9 math; flag protocol rebuilt).  R9 at 1.18us/step had ~50%
// of the step in flag mechanics: 6 serial flag loads/step in the LSTM group,
// 64-lane redundant flag stores, tight spins from ahead-running waves
// contending the LDS pipe.  This round:
//   * hflag[4] -> ONE counter hcnt (atomicAdd/wave after h-write; h(t) done
//     <=> hcnt >= 4(t+1)).  Safe: every wave gates on the previous full step,
//     so per-wave skew <= 1 and hcnt cannot spuriously reach 4(t+2).
//   * A1 flags chained: wave7 waits wave6 then publishes a7; consumers check
//     a7 only (1 load implies both).
//   * flag stores lane0-only; s_sleep(1) backoff on back-pressure waits.
//   * z fed back via v_readlane (SGPR broadcast) instead of 5 ds_bpermute.
// Wave roles unchanged from R9 (quad-gate LSTM 0-3, z-chain 4-5, A1 6-7).
// Back-pressure proofs: a7>=t => both A1 waves read hring[t] (chain);
// ttag>=t => both z waves consumed A1ring[t] (pf coupling: wave4 finishing t
// requires pf[1]>=t which wave5 sets after its A1 reads).
// ---------------------------------------------------------------------------
__global__ __launch_bounds__(512)
__attribute__((amdgpu_waves_per_eu(2, 2)))
void scan_kernel(
    const float* __restrict__ obs,
    const float* __restrict__ Wih,
    const float* __restrict__ Whh,
    const float* __restrict__ bih,
    const float* __restrict__ bhh,
    const float* __restrict__ tw1,
    const float* __restrict__ tb1,
    const float* __restrict__ tg,
    const float* __restrict__ tbeta,
    const float* __restrict__ tw2,
    const float* __restrict__ tb2,
    const float* __restrict__ tw3,
    const float* __restrict__ tb3,
    const float* __restrict__ z0m,
    const float* __restrict__ z0lv,
    float* __restrict__ out_tm,
    float* __restrict__ out_tlv)
{
    __shared__ __align__(16) float hring[8][64];
    __shared__ __align__(16) float oring[8][32];
    __shared__ __align__(16) float A1ring[8][128];
    __shared__ __align__(16) float h1w[2][64];
    __shared__ float p2s[2][2][64];      // [t&1][wave][lane]
    __shared__ int hcnt;                 // 4*(t+1) when h(t) complete
    __shared__ int a6, a7;               // A1 producer flags (chained)
    __shared__ int pf[2];
    __shared__ int ttag;

    const int tid  = threadIdx.x;
    const int wid  = tid >> 6;
    const int lane = tid & 63;
    const int b    = blockIdx.x;

    vf32 V0, V1, V2;
    #pragma unroll
    for (int k = 0; k < 32; k++) { V0[k]=0.f; V1[k]=0.f; V2[k]=0.f; }

    float biasg = 0.f, b1r = 0.f, gr = 0.f, betar = 0.f, b2r = 0.f, b3r = 0.f;
    float c_st = 0.f, carry = 0.f;

    if (wid < 4) {
        const int g  = lane & 3;
        const int uu = wid*16 + (lane >> 2);
        const int row = g*64 + uu;
        biasg = bih[row] + bhh[row];
        #pragma unroll
        for (int k = 0; k < 32; k++) V0[k] = Wih[row*32 + k];
        #pragma unroll
        for (int k = 0; k < 32; k++) V1[k] = Whh[row*64 + k];
        #pragma unroll
        for (int k = 0; k < 32; k++) V2[k] = Whh[row*64 + 32 + k];
        if (g == 1 && uu < 32) carry = obs[((size_t)b*T_ + 4)*32 + uu];
    } else if (wid < 6) {
        const int ks = wid - 4;                      // K-slice / h1-half
        #pragma unroll
        for (int k = 0; k < 32; k++) V0[k] = tw2[lane*128 + ks*64 + k];
        #pragma unroll
        for (int k = 0; k < 32; k++) V1[k] = tw2[lane*128 + ks*64 + 32 + k];
        #pragma unroll
        for (int k = 0; k < 5; k++) {
            V2[k]     = tw1[lane*69 + 64 + k];        // Bz, row r0 = lane
            V2[5 + k] = tw1[(64 + lane)*69 + 64 + k]; // Bz, row r1 = 64+lane
        }
        const int r = ks*64 + lane;                  // own h1 row
        gr = tg[r]; betar = tbeta[r];
        b2r = tb2[lane];                             // both waves (symmetric)
        if (lane < 40) {
            #pragma unroll
            for (int k = 0; k < 16; k++)
                V2[10 + k] = tw3[(lane>>2)*64 + (lane&3)*16 + k];
            b3r = tb3[lane >> 2];
        }
    } else {
        const int r = (wid - 6)*64 + lane;           // A1 row
        #pragma unroll
        for (int k = 0; k < 32; k++) V0[k] = tw1[r*69 + k];
        #pragma unroll
        for (int k = 0; k < 32; k++) V1[k] = tw1[r*69 + 32 + k];
        b1r = tb1[r];
    }

    // LDS / output init
    if (tid < 64) hring[7][tid] = 0.f;               // h(-1) at slot (-1)&7
    if (tid < 128) oring[tid >> 5][tid & 31] = obs[(size_t)b*T_*32 + tid]; // t=0..3
    if (tid < 5) {
        out_tm [(size_t)b*T_*5 + tid] = z0m[tid];
        out_tlv[(size_t)b*T_*5 + tid] = z0lv[tid];
    }
    if (tid == 0) { hcnt = 0; a6 = 0; a7 = 0; pf[0] = 0; pf[1] = 0; ttag = 0; }
    __syncthreads();        // the ONLY workgroup barrier

    if (wid < 4) {
        // ======================= LSTM group =======================
        const int g  = lane & 3;
        const int uu = wid*16 + (lane >> 2);
        for (int t = 0; t < T_; ++t) {
            wait_ge(&hcnt, 4*t);            // h(t-1) complete (1 load)
            wait_ge_slp(&a7, t - 8);        // hring back-pressure (backoff)

            const float4* ob = (const float4*)oring[t & 7];
            const float4* hp = (const float4*)hring[(t - 1) & 7];
            float a0 = biasg, a1 = 0.f, a2 = 0.f, a3 = 0.f;
            #pragma unroll
            for (int k4 = 0; k4 < 8; k4++) {
                float4 o = ob[k4];
                a0 += V0[k4*4+0]*o.x;
                a1 += V0[k4*4+1]*o.y;
                a2 += V0[k4*4+2]*o.z;
                a3 += V0[k4*4+3]*o.w;
            }
            #pragma unroll
            for (int k4 = 0; k4 < 8; k4++) {
                float4 h = hp[k4];
                a0 += V1[k4*4+0]*h.x;
                a1 += V1[k4*4+1]*h.y;
                a2 += V1[k4*4+2]*h.z;
                a3 += V1[k4*4+3]*h.w;
            }
            #pragma unroll
            for (int k4 = 0; k4 < 8; k4++) {
                float4 h = hp[8 + k4];
                a0 += V2[k4*4+0]*h.x;
                a1 += V2[k4*4+1]*h.y;
                a2 += V2[k4*4+2]*h.z;
                a3 += V2[k4*4+3]*h.w;
            }
            const float G = (a0 + a1) + (a2 + a3);

            // quad all-gather via DPP
            const float x1 = dpp_mov<0xB1>(G);   // lane^1
            const float x2 = dpp_mov<0x4E>(G);   // lane^2
            const float x3 = dpp_mov<0x1B>(G);   // lane^3
            const bool c1 = (g & 1), c2 = (g & 2);
            float iv = c2 ? (c1 ? x3 : x2) : (c1 ? x1 : G );
            float fv = c2 ? (c1 ? x2 : x3) : (c1 ? G  : x1);
            float gv = c2 ? (c1 ? x1 : G ) : (c1 ? x3 : x2);
            float ov = c2 ? (c1 ? G  : x1) : (c1 ? x2 : x3);

            iv = fast_sigmoid(iv);
            fv = fast_sigmoid(fv);
            gv = fast_tanh(gv);
            ov = fast_sigmoid(ov);
            c_st = fv*c_st + iv*gv;
            const float hv = ov * fast_tanh(c_st);

            if (g == 0) hring[t & 7][uu] = hv;
            if (g == 1 && uu < 32 && t + 4 < T_) oring[(t + 4) & 7][uu] = carry;
            if (lane == 0)
                __hip_atomic_fetch_add(&hcnt, 1, __ATOMIC_RELEASE,
                                       __HIP_MEMORY_SCOPE_WORKGROUP);
            if (g == 1 && uu < 32 && t + 5 < T_)
                carry = obs[((size_t)b*T_ + t + 5)*32 + uu];
        }
    } else if (wid < 6) {
        // =============== trans group (symmetric z-chain) ===============
        const int ks = wid - 4;
        float zr0 = z0m[0], zr1 = z0m[1], zr2 = z0m[2],
              zr3 = z0m[3], zr4 = z0m[4];
        for (int t = 1; t < T_; ++t) {
            wait_ge(&a7, t);                // A1(t) complete (1 load, tight)

            // mv1: 2 rows/lane; z from registers
            float a0 = A1ring[t & 7][lane]
                     + V2[0]*zr0 + V2[1]*zr1 + V2[2]*zr2 + V2[3]*zr3 + V2[4]*zr4;
            float a1 = A1ring[t & 7][64 + lane]
                     + V2[5]*zr0 + V2[6]*zr1 + V2[7]*zr2 + V2[8]*zr3 + V2[9]*zr4;
            // LN stats over 128 rows (VALU reduction)
            const float s1 = wave_sum64(a0 + a1);
            const float s2 = wave_sum64(a0*a0 + a1*a1);
            const float mean = s1 * (1.0f/128.0f);
            const float var  = fmaxf(s2 * (1.0f/128.0f) - mean*mean, 0.0f);
            const float rs   = rsqrtf(var + 1e-5f);
            const float aown = ks ? a1 : a0;
            const float h1v  = fast_tanh((aown - mean)*rs*gr + betar);

            h1w[ks][lane] = h1v;                     // wave-local strip
            __builtin_amdgcn_wave_barrier();

            // mv2 partial over own K-slice
            float p0 = 0.f, p1 = 0.f, p2 = 0.f, p3 = 0.f;
            const float4* h4 = (const float4*)h1w[ks];
            #pragma unroll
            for (int k4 = 0; k4 < 8; k4++) {
                float4 h = h4[k4];
                p0 += V0[k4*4+0]*h.x;
                p1 += V0[k4*4+1]*h.y;
                p2 += V0[k4*4+2]*h.z;
                p3 += V0[k4*4+3]*h.w;
            }
            #pragma unroll
            for (int k4 = 0; k4 < 8; k4++) {
                float4 h = h4[8 + k4];
                p0 += V1[k4*4+0]*h.x;
                p1 += V1[k4*4+1]*h.y;
                p2 += V1[k4*4+2]*h.z;
                p3 += V1[k4*4+3]*h.w;
            }
            const float p = (p0 + p1) + (p2 + p3);

            // exchange partials (parity buffer; lane0 flags)
            p2s[t & 1][ks][lane] = p;
            if (lane == 0) st_rel(&pf[ks], t);
            wait_ge(&pf[ks ^ 1], t);
            const float pother = p2s[t & 1][ks ^ 1][lane];

            // BOTH waves: h2, mv3, z
            const float h2v = fast_tanh(b2r + p + pother);
            const int pp = lane & 3;
            float ac0 = 0.f, ac1 = 0.f, ac2 = 0.f, ac3 = 0.f;
            #pragma unroll
            for (int k = 0; k < 4; k++) {
                ac0 += V2[10 + k]      * __shfl(h2v, pp*16 + k,      64);
                ac1 += V2[10 + 4 + k]  * __shfl(h2v, pp*16 + 4 + k,  64);
                ac2 += V2[10 + 8 + k]  * __shfl(h2v, pp*16 + 8 + k,  64);
                ac3 += V2[10 + 12 + k] * __shfl(h2v, pp*16 + 12 + k, 64);
            }
            float acc = (ac0 + ac1) + (ac2 + ac3);
            acc += dpp_mov<0xB1>(acc);
            acc += dpp_mov<0x4E>(acc);       // lanes 4j..4j+3 hold row-j total
            const float val = b3r + acc;

            if (ks == 0) {
                if (pp == 0 && lane < 40) {
                    const int j = lane >> 2;          // 0..9
                    const size_t row = (size_t)b*T_ + t;
                    if (j < 5) out_tm[row*5 + j] = val;
                    else out_tlv[row*5 + (j - 5)] =
                             fminf(10.0f, fmaxf(-10.0f, val));
                }
                if (lane == 0) st_rel(&ttag, t);   // A1 ring back-pressure
            }
            // z feedback via SGPR broadcast (VALU/SALU; was 5 ds_bpermute)
            zr0 = readlane_f(val, 0);
            zr1 = readlane_f(val, 4);
            zr2 = readlane_f(val, 8);
            zr3 = readlane_f(val, 12);
            zr4 = readlane_f(val, 16);
        }
    } else {
        // ======================= A1 producers =======================
        const int r = (wid - 6)*64 + lane;
        for (int t = 1; t < T_; ++t) {
            wait_ge(&hcnt, 4*(t + 1));      // h(t) complete (1 load)
            wait_ge_slp(&ttag, t - 8);      // A1 ring back-pressure (backoff)

            const float4* hv4 = (const float4*)hring[t & 7];
            float s0 = b1r, s1 = 0.f, s2 = 0.f, s3 = 0.f;
            #pragma unroll
            for (int k4 = 0; k4 < 8; k4++) {
                float4 h = hv4[k4];
                s0 += V0[k4*4+0]*h.x;
                s1 += V0[k4*4+1]*h.y;
                s2 += V0[k4*4+2]*h.z;
                s3 += V0[k4*4+3]*h.w;
            }
            #pragma unroll
            for (int k4 = 0; k4 < 8; k4++) {
                float4 h = hv4[8 + k4];
                s0 += V1[k4*4+0]*h.x;
                s1 += V1[k4*4+1]*h.y;
                s2 += V1[k4*4+2]*h.z;
                s3 += V1[k4*4+3]*h.w;
            }
            A1ring[t & 7][r] = (s0 + s1) + (s2 + s3);
            if (wid == 6) {
                if (lane == 0) st_rel(&a6, t);
            } else {
                wait_ge(&a6, t);            // chain: a7 implies both
                if (lane == 0) st_rel(&a7, t);
            }
        }
    }
}

// ---------------------------------------------------------------------------
// Observation decoder (R9 version, validated): DPP/permlane butterfly,
// per-wave LDS strips, broadcast float4 re-reads, 4-way split accumulators.
// ---------------------------------------------------------------------------
#define DEC_BLOCKS 512

__global__ __launch_bounds__(512) void dec_kernel(
    const float* __restrict__ ow1,
    const float* __restrict__ ob1,
    const float* __restrict__ og,
    const float* __restrict__ obeta,
    const float* __restrict__ ow2,
    const float* __restrict__ ob2,
    const float* __restrict__ ow3,
    const float* __restrict__ ob3,
    const float* __restrict__ tmeans,
    float* __restrict__ out_om,
    float* __restrict__ out_olv)
{
    __shared__ float w1s[640];
    __shared__ float b1s[128], gs[128], bes[128];
    __shared__ float w2s[8192];
    __shared__ float b2s[64];
    __shared__ float w3s[4096];
    __shared__ float b3s[64];
    __shared__ __align__(16) float h1s[8][128];
    __shared__ __align__(16) float h2s[8][64];

    const int tid = threadIdx.x;
    for (int idx = tid; idx < 640; idx += 512) w1s[idx] = ow1[idx];
    for (int idx = tid; idx < 128; idx += 512) {
        b1s[idx] = ob1[idx]; gs[idx] = og[idx]; bes[idx] = obeta[idx];
    }
    for (int idx = tid; idx < 8192; idx += 512) {
        int k = idx >> 6, j = idx & 63;
        w2s[idx] = ow2[j*128 + k];
    }
    for (int idx = tid; idx < 4096; idx += 512) {
        int k = idx >> 6, j = idx & 63;
        w3s[idx] = ow3[j*64 + k];
    }
    for (int idx = tid; idx < 64; idx += 512) { b2s[idx] = ob2[idx]; b3s[idx] = ob3[idx]; }
    __syncthreads();

    const int lane   = tid & 63;
    const int wv     = tid >> 6;
    const int gwave  = (blockIdx.x * 512 + tid) >> 6;
    const int nwaves = DEC_BLOCKS * 8;
    const int j0 = lane, j1 = lane + 64;

    for (int row = gwave; row < B_*T_; row += nwaves) {
        const float z0v = tmeans[(size_t)row*5 + 0];
        const float z1v = tmeans[(size_t)row*5 + 1];
        const float z2v = tmeans[(size_t)row*5 + 2];
        const float z3v = tmeans[(size_t)row*5 + 3];
        const float z4v = tmeans[(size_t)row*5 + 4];

        float a = b1s[j0] + w1s[j0*5+0]*z0v + w1s[j0*5+1]*z1v + w1s[j0*5+2]*z2v
                + w1s[j0*5+3]*z3v + w1s[j0*5+4]*z4v;
        float bb = b1s[j1] + w1s[j1*5+0]*z0v + w1s[j1*5+1]*z1v + w1s[j1*5+2]*z2v
                 + w1s[j1*5+3]*z3v + w1s[j1*5+4]*z4v;
        const float s1 = wave_sum64(a + bb);
        const float s2 = wave_sum64(a*a + bb*bb);
        const float mean = s1 * (1.0f/128.0f);
        const float var  = fmaxf(s2 * (1.0f/128.0f) - mean*mean, 0.0f);
        const float rs   = rsqrtf(var + 1e-5f);
        const float h1a  = fast_tanh((a  - mean)*rs*gs[j0] + bes[j0]);
        const float h1b  = fast_tanh((bb - mean)*rs*gs[j1] + bes[j1]);

        h1s[wv][lane]      = h1a;
        h1s[wv][64 + lane] = h1b;
        __builtin_amdgcn_wave_barrier();

        float acc2a = b2s[lane], acc2b = 0.f, acc2c = 0.f, acc2d = 0.f;
        const float4* h14 = (const float4*)(h1s[wv]);
        #pragma unroll
        for (int k4 = 0; k4 < 32; k4++) {
            float4 h = h14[k4];
            acc2a += h.x * w2s[(k4*4+0)*64 + lane];
            acc2b += h.y * w2s[(k4*4+1)*64 + lane];
            acc2c += h.z * w2s[(k4*4+2)*64 + lane];
            acc2d += h.w * w2s[(k4*4+3)*64 + lane];
        }
        const float h2v = fast_tanh(acc2a + acc2b + acc2c + acc2d);

        h2s[wv][lane] = h2v;
        __builtin_amdgcn_wave_barrier();

        float acc3a = b3s[lane], acc3b = 0.f, acc3c = 0.f, acc3d = 0.f;
        const float4* h24 = (const float4*)(h2s[wv]);
        #pragma unroll
        for (int k4 = 0; k4 < 16; k4++) {
            float4 h = h24[k4];
            acc3a += h.x * w3s[(k4*4+0)*64 + lane];
            acc3b += h.y * w3s[(k4*4+1)*64 + lane];
            acc3c += h.z * w3s[(k4*4+2)*64 + lane];
            acc3d += h.w * w3s[(k4*4+3)*64 + lane];
        }
        const float acc3 = acc3a + acc3b + acc3c + acc3d;

        if (lane < 32) {
            out_om[(size_t)row*32 + lane] = acc3;
        } else {
            out_olv[(size_t)row*32 + (lane - 32)] = fminf(10.0f, fmaxf(-10.0f, acc3));
        }
    }
}

extern "C" void kernel_launch(void* const* d_in, const int* in_sizes, int n_in,
                              void* d_out, int out_size, void* d_ws, size_t ws_size,
                              hipStream_t stream) {
    const float* obs  = (const float*)d_in[0];
    const float* Wih  = (const float*)d_in[1];
    const float* Whh  = (const float*)d_in[2];
    const float* bih  = (const float*)d_in[3];
    const float* bhh  = (const float*)d_in[4];
    const float* tw1  = (const float*)d_in[5];
    const float* tb1  = (const float*)d_in[6];
    const float* tg   = (const float*)d_in[7];
    const float* tbe  = (const float*)d_in[8];
    const float* tw2  = (const float*)d_in[9];
    const float* tb2  = (const float*)d_in[10];
    const float* tw3  = (const float*)d_in[11];
    const float* tb3  = (const float*)d_in[12];
    const float* ow1  = (const float*)d_in[13];
    const float* ob1  = (const float*)d_in[14];
    const float* og   = (const float*)d_in[15];
    const float* obe  = (const float*)d_in[16];
    const float* ow2  = (const float*)d_in[17];
    const float* ob2  = (const float*)d_in[18];
    const float* ow3  = (const float*)d_in[19];
    const float* ob3  = (const float*)d_in[20];
    const float* z0m  = (const float*)d_in[21];
    const float* z0lv = (const float*)d_in[22];

    float* out0 = (float*)d_out;                   // obs_means   (B,T,32)
    float* out1 = out0 + (size_t)B_*T_*32;         // obs_logvars (B,T,32)
    float* out2 = out1 + (size_t)B_*T_*32;         // trans_means (B,T,5)
    float* out3 = out2 + (size_t)B_*T_*5;          // trans_logvars

    scan_kernel<<<B_, 512, 0, stream>>>(obs, Wih, Whh, bih, bhh,
                                        tw1, tb1, tg, tbe, tw2, tb2, tw3, tb3,
                                        z0m, z0lv, out2, out3);

    dec_kernel<<<DEC_BLOCKS, 512, 0, stream>>>(
        ow1, ob1, og, obe, ow2, ob2, ow3, ob3, out2, out0, out1);
}